// Round 1
// baseline (485.284 us; speedup 1.0000x reference)
//
#include <hip/hip_runtime.h>
#include <math.h>

// Problem constants (from reference): B=64, Q=900, T=128, NUM_CLASSES=13
#define B_    64
#define Q_    900
#define T_    128
#define NCLS  13
#define NCLS1 14
#define NTH   256
#define NWV   (NTH / 64)

// Block-wide f64 sum; result valid on tid 0. All threads must call.
__device__ __forceinline__ double blockSum(double v, double* sAcc, int tid) {
#pragma unroll
    for (int off = 32; off > 0; off >>= 1) v += __shfl_down(v, off);
    if ((tid & 63) == 0) sAcc[tid >> 6] = v;
    __syncthreads();
    if (tid == 0) {
#pragma unroll
        for (int w = 1; w < NWV; ++w) v += sAcc[w];
    }
    __syncthreads();
    return v;
}

// One block per image. Stages softmax probs + boxes into LDS, runs the exact
// Jonker-Volgenant algorithm (rows = targets n=128, cols = queries m=900,
// matching the reference's transposed path), then computes the matched
// class + bbox losses. Cost entries are f32 (same op order as the jnp
// reference); JV duals are f64 (reference casts C to float64). argmin ties
// break to the SMALLEST column index (np.argmin semantics).
extern "C" __global__ __launch_bounds__(NTH)
void detr_hungarian_loss(const float* __restrict__ pc,    // [B,Q,14]
                         const float* __restrict__ pbx,   // [B,Q,4]
                         const int*   __restrict__ tl,    // [B,T]
                         const float* __restrict__ tbx,   // [B,T,4]
                         double* __restrict__ perImg)     // [B]
{
    const int b   = blockIdx.x;
    const int tid = threadIdx.x;

    __shared__ float  sProb[Q_ * NCLS];   // softmax probs, classes 0..12
    __shared__ float  sPb[Q_ * 4];        // predicted boxes
    __shared__ float  sLse[Q_];           // logsumexp per query (for CE)
    __shared__ float  sTb[T_ * 4];        // target boxes
    __shared__ int    sLab[T_];           // target labels
    __shared__ double sV[Q_ + 1];
    __shared__ double sMinv[Q_ + 1];
    __shared__ double sU[T_ + 1];
    __shared__ int    sP[Q_ + 1];         // col -> assigned row (1-based)
    __shared__ int    sWay[Q_ + 1];       // also reused as tc[] later
    __shared__ unsigned char sUsed[Q_ + 1];
    __shared__ int    sPred[T_];          // target t -> matched query
    __shared__ double sRv[NWV];
    __shared__ int    sRi[NWV];
    __shared__ double sAcc[NWV];
    __shared__ int    sJ0, sI0, sBrk;
    __shared__ double sDelta;

    const double DINF = __builtin_inf();

    const float* pcb = pc  + (size_t)b * Q_ * NCLS1;
    const float* pbb = pbx + (size_t)b * Q_ * 4;
    const float* tbb = tbx + (size_t)b * T_ * 4;
    const int*   tlb = tl  + (size_t)b * T_;

    // ---- stage inputs + f32 softmax (same op order as jax.nn.softmax) ----
    for (int q = tid; q < Q_; q += NTH) {
        float x[NCLS1];
#pragma unroll
        for (int c = 0; c < NCLS1; ++c) x[c] = pcb[q * NCLS1 + c];
        float mx = x[0];
#pragma unroll
        for (int c = 1; c < NCLS1; ++c) mx = fmaxf(mx, x[c]);
        float ex[NCLS1];
        float sum = 0.f;
#pragma unroll
        for (int c = 0; c < NCLS1; ++c) { ex[c] = expf(x[c] - mx); sum += ex[c]; }
#pragma unroll
        for (int c = 0; c < NCLS; ++c) sProb[q * NCLS + c] = ex[c] / sum;  // true division, like unnormalized/sum
        sLse[q] = mx + logf(sum);
        const float4 bb4 = reinterpret_cast<const float4*>(pbb)[q];
        sPb[q * 4 + 0] = bb4.x; sPb[q * 4 + 1] = bb4.y;
        sPb[q * 4 + 2] = bb4.z; sPb[q * 4 + 3] = bb4.w;
    }
    for (int t = tid; t < T_; t += NTH) {
        sLab[t] = tlb[t];
        const float4 tb4 = reinterpret_cast<const float4*>(tbb)[t];
        sTb[t * 4 + 0] = tb4.x; sTb[t * 4 + 1] = tb4.y;
        sTb[t * 4 + 2] = tb4.z; sTb[t * 4 + 3] = tb4.w;
    }
    for (int j = tid; j <= Q_; j += NTH) { sV[j] = 0.0; sP[j] = 0; sWay[j] = 0; }
    for (int i = tid; i <= T_; i += NTH) sU[i] = 0.0;
    __syncthreads();

    // ---- JV Hungarian ----
    for (int i = 1; i <= T_; ++i) {
        if (tid == 0) { sP[0] = i; sJ0 = 0; }
        for (int j = tid; j <= Q_; j += NTH) { sMinv[j] = DINF; sUsed[j] = 0; }
        __syncthreads();
        for (;;) {
            if (tid == 0) { sUsed[sJ0] = 1; sI0 = sP[sJ0]; }
            __syncthreads();
            const int    i0  = sI0;
            const int    j0  = sJ0;
            const double ui0 = sU[i0];
            const int    tr  = i0 - 1;
            const int    lab = sLab[tr];
            const float  t0 = sTb[tr * 4 + 0], t1 = sTb[tr * 4 + 1];
            const float  t2 = sTb[tr * 4 + 2], t3 = sTb[tr * 4 + 3];

            // scan free columns: update minv/way, track local argmin.
            // j increases within each thread, strict < keeps smallest j on ties.
            double bestv = DINF;
            int    bestj = Q_ + 1;
            for (int j = 1 + tid; j <= Q_; j += NTH) {
                if (!sUsed[j]) {
                    const int q = j - 1;
                    // cost_bbox: sequential f32 sum of 4 abs-diffs (matches jnp .sum(-1))
                    float cb = fabsf(sPb[q * 4 + 0] - t0);
                    cb = cb + fabsf(sPb[q * 4 + 1] - t1);
                    cb = cb + fabsf(sPb[q * 4 + 2] - t2);
                    cb = cb + fabsf(sPb[q * 4 + 3] - t3);
                    const float cost = cb - sProb[q * NCLS + lab];  // (-prob)+cb, f32
                    const double cur = (double)cost - ui0 - sV[j];
                    double mv = sMinv[j];
                    if (cur < mv) { sMinv[j] = cur; sWay[j] = j0; mv = cur; }
                    if (mv < bestv) { bestv = mv; bestj = j; }
                }
            }
            // block argmin with first-index tie-break
#pragma unroll
            for (int off = 32; off > 0; off >>= 1) {
                const double ov = __shfl_down(bestv, off);
                const int    oj = __shfl_down(bestj, off);
                if (ov < bestv || (ov == bestv && oj < bestj)) { bestv = ov; bestj = oj; }
            }
            if ((tid & 63) == 0) { sRv[tid >> 6] = bestv; sRi[tid >> 6] = bestj; }
            __syncthreads();
            if (tid == 0) {
                double dv = sRv[0]; int dj = sRi[0];
#pragma unroll
                for (int w = 1; w < NWV; ++w) {
                    if (sRv[w] < dv || (sRv[w] == dv && sRi[w] < dj)) { dv = sRv[w]; dj = sRi[w]; }
                }
                sDelta = dv; sJ0 = dj; sBrk = (sP[dj] == 0) ? 1 : 0;
            }
            __syncthreads();
            const double delta = sDelta;
            // u[p[used]] += delta; v[used] -= delta; minv[free] -= delta.
            // p[] values over used columns are distinct rows -> no write races.
            for (int j = tid; j <= Q_; j += NTH) {
                if (sUsed[j]) { sU[sP[j]] += delta; sV[j] -= delta; }
                else          { sMinv[j] -= delta; }
            }
            __syncthreads();
            if (sBrk) break;
        }
        if (tid == 0) {  // augmenting path (short; sequential)
            int j0 = sJ0;
            while (j0 != 0) {
                const int j1 = sWay[j0];
                sP[j0] = sP[j1];
                j0 = j1;
            }
        }
        __syncthreads();
    }

    // ---- extract matching: pred query for each target (tgt_idx is identity) ----
    for (int j = 1 + tid; j <= Q_; j += NTH) {
        const int pi = sP[j];
        if (pi > 0) sPred[pi - 1] = j - 1;
    }
    __syncthreads();

    // ---- tc[] (reuse sWay): NUM_CLASSES default, matched queries get label ----
    int* sTc = sWay;
    for (int q = tid; q < Q_; q += NTH) sTc[q] = NCLS;
    __syncthreads();
    for (int t = tid; t < T_; t += NTH) sTc[sPred[t]] = sLab[t];  // sPred distinct
    __syncthreads();

    // ---- weighted CE over all queries ----
    double swn = 0.0, sw = 0.0;
    for (int q = tid; q < Q_; q += NTH) {
        const int   c   = sTc[q];
        const float xv  = pcb[q * NCLS1 + c];
        const float nll = sLse[q] - xv;              // -log_softmax[tc]
        const double w  = (c == NCLS) ? (double)0.05f : 1.0;
        swn += w * (double)nll;
        sw  += w;
    }

    // ---- bbox L1 + GIoU over matched pairs ----
    double l1s = 0.0, gs = 0.0;
    for (int t = tid; t < T_; t += NTH) {
        const int q = sPred[t];
        const float p0 = sPb[q * 4 + 0], p1 = sPb[q * 4 + 1];
        const float p2 = sPb[q * 4 + 2], p3 = sPb[q * 4 + 3];
        const float t0 = sTb[t * 4 + 0], t1 = sTb[t * 4 + 1];
        const float t2 = sTb[t * 4 + 2], t3 = sTb[t * 4 + 3];
        l1s += (double)fabsf(p0 - t0) + (double)fabsf(p1 - t1)
             + (double)fabsf(p2 - t2) + (double)fabsf(p3 - t3);
        const float ax1 = p0 - 0.5f * p2, ay1 = p1 - 0.5f * p3;
        const float ax2 = p0 + 0.5f * p2, ay2 = p1 + 0.5f * p3;
        const float bx1 = t0 - 0.5f * t2, by1 = t1 - 0.5f * t3;
        const float bx2 = t0 + 0.5f * t2, by2 = t1 + 0.5f * t3;
        const double a1 = (double)(ax2 - ax1) * (double)(ay2 - ay1);
        const double a2 = (double)(bx2 - bx1) * (double)(by2 - by1);
        const double ltx = fmax((double)ax1, (double)bx1);
        const double lty = fmax((double)ay1, (double)by1);
        const double rbx = fmin((double)ax2, (double)bx2);
        const double rby = fmin((double)ay2, (double)by2);
        const double iw = fmax(rbx - ltx, 0.0), ih = fmax(rby - lty, 0.0);
        const double inter = iw * ih;
        const double uni   = a1 + a2 - inter;
        const double iou   = inter / uni;
        const double cx1 = fmin((double)ax1, (double)bx1);
        const double cy1 = fmin((double)ay1, (double)by1);
        const double cx2 = fmax((double)ax2, (double)bx2);
        const double cy2 = fmax((double)ay2, (double)by2);
        const double ac  = (cx2 - cx1) * (cy2 - cy1);
        const double giou = iou - (ac - uni) / ac;
        gs += 1.0 - giou;
    }

    const double swnT = blockSum(swn, sAcc, tid);
    const double swT  = blockSum(sw,  sAcc, tid);
    const double l1T  = blockSum(l1s, sAcc, tid);
    const double gsT  = blockSum(gs,  sAcc, tid);
    if (tid == 0) {
        const double cls = swnT / swT;
        const double bb  = 5.0 * (l1T / (double)(T_ * 4)) + 2.0 * (gsT / (double)T_);
        perImg[b] = cls + bb;
    }
}

extern "C" __global__ void detr_finalize(const double* __restrict__ perImg,
                                         float* __restrict__ out)
{
    const int l = threadIdx.x;   // 64 threads, one wave
    double v = perImg[l];
#pragma unroll
    for (int off = 32; off > 0; off >>= 1) v += __shfl_down(v, off);
    if (l == 0) out[0] = (float)(v / 8192.0);
}

extern "C" void kernel_launch(void* const* d_in, const int* in_sizes, int n_in,
                              void* d_out, int out_size, void* d_ws, size_t ws_size,
                              hipStream_t stream) {
    const float* pc  = (const float*)d_in[0];   // predicted_class [64,900,14]
    const float* pbx = (const float*)d_in[1];   // predicted_bbox  [64,900,4]
    const int*   tl  = (const int*)  d_in[2];   // target_labels   [64,128]
    const float* tbx = (const float*)d_in[3];   // target_boxes    [64,128,4]
    double* wsl = (double*)d_ws;                // 64 doubles of scratch
    (void)in_sizes; (void)n_in; (void)out_size; (void)ws_size;

    detr_hungarian_loss<<<dim3(B_), dim3(NTH), 0, stream>>>(pc, pbx, tl, tbx, wsl);
    detr_finalize<<<dim3(1), dim3(64), 0, stream>>>(wsl, (float*)d_out);
}

// Round 2
// 484.830 us; speedup vs baseline: 1.0009x; 1.0009x over previous
//
#include <hip/hip_runtime.h>
#include <math.h>

// Problem constants (from reference): B=64, Q=900, T=128, NUM_CLASSES=13
#define B_    64
#define Q_    900
#define T_    128
#define NCLS  13
#define NCLS1 14
#define NK    15          // columns per lane: lane owns j-1 = lane + 64*k, k<NK

// Wave-wide f64 sum via xor butterfly; every lane ends with the total.
__device__ __forceinline__ double waveSum(double v) {
#pragma unroll
    for (int m = 1; m < 64; m <<= 1) v += __shfl_xor(v, m);
    return v;
}

// One 64-lane wave per image. Per-column JV state (v, minv, used, pred boxes)
// lives in registers of the owning lane; u/p/way in LDS. Single-wave workgroup
// makes __syncthreads() near-free and the argmin a pure-shuffle butterfly.
// Algorithm is iteration-for-iteration identical to the reference e-maxx JV
// (f32 costs in jnp op order, f64 duals, np.argmin first-index tie-break).
extern "C" __global__ __launch_bounds__(64)
void detr_hungarian_loss(const float* __restrict__ pc,    // [B,Q,14]
                         const float* __restrict__ pbx,   // [B,Q,4]
                         const int*   __restrict__ tl,    // [B,T]
                         const float* __restrict__ tbx,   // [B,T,4]
                         double* __restrict__ perImg)     // [B]
{
    const int b    = blockIdx.x;
    const int lane = threadIdx.x;          // 0..63

    __shared__ float  sProb[Q_ * NCLS];    // softmax probs, classes 0..12
    __shared__ float  sLse[Q_];            // logsumexp per query (for CE)
    __shared__ float4 sTb4[T_];            // target boxes
    __shared__ int    sLab[T_];            // target labels
    __shared__ double sU[T_ + 1];          // row duals (1-based)
    __shared__ int    sP[Q_ + 1];          // col -> assigned row (1-based)
    __shared__ int    sWay[Q_ + 1];
    __shared__ int    sPred[T_];           // target t -> matched query
    __shared__ int    sTc[Q_];             // per-query CE target class

    const double DINF = __builtin_inf();

    const float* pcb = pc  + (size_t)b * Q_ * NCLS1;
    const float* pbb = pbx + (size_t)b * Q_ * 4;
    const float* tbb = tbx + (size_t)b * T_ * 4;
    const int*   tlb = tl  + (size_t)b * T_;

    // ---- stage: f32 softmax (same op order as jax.nn.softmax) + boxes ----
    float4   pbr[NK];                      // this lane's predicted boxes
    unsigned validMask = 0;
#pragma unroll
    for (int k = 0; k < NK; ++k) {
        const int q = (k << 6) + lane;
        if (q < Q_) {
            validMask |= 1u << k;
            float x[NCLS1];
#pragma unroll
            for (int c = 0; c < NCLS1; ++c) x[c] = pcb[q * NCLS1 + c];
            float mx = x[0];
#pragma unroll
            for (int c = 1; c < NCLS1; ++c) mx = fmaxf(mx, x[c]);
            float ex[NCLS1];
            float sum = 0.f;
#pragma unroll
            for (int c = 0; c < NCLS1; ++c) { ex[c] = expf(x[c] - mx); sum += ex[c]; }
#pragma unroll
            for (int c = 0; c < NCLS; ++c) sProb[q * NCLS + c] = ex[c] / sum;
            sLse[q] = mx + logf(sum);
            pbr[k] = reinterpret_cast<const float4*>(pbb)[q];
        } else {
            pbr[k] = make_float4(0.f, 0.f, 0.f, 0.f);
        }
    }
    for (int t = lane; t < T_; t += 64) {
        sLab[t] = tlb[t];
        sTb4[t] = reinterpret_cast<const float4*>(tbb)[t];
    }
    for (int j = lane; j <= Q_; j += 64) sP[j] = 0;
    for (int i = lane; i <= T_; i += 64) sU[i] = 0.0;
    double v[NK];
#pragma unroll
    for (int k = 0; k < NK; ++k) v[k] = 0.0;
    __syncthreads();

    // ---- JV Hungarian (rows = targets, cols = queries) ----
    for (int i = 1; i <= T_; ++i) {
        double minv[NK];
#pragma unroll
        for (int k = 0; k < NK; ++k) minv[k] = DINF;
        unsigned used = ~validMask;        // invalid columns pre-marked used
        int j0 = 0;
        int i0 = i;                        // p[0] = i
        for (;;) {
            // used[j0] = True (column 0 handled via lane-0 special add below)
            if (j0 != 0) {
                const int col = j0 - 1;
                if ((col & 63) == lane) used |= 1u << (col >> 6);
            }
            const double u_i0 = sU[i0];
            const float4 t4   = sTb4[i0 - 1];
            const int    lab  = sLab[i0 - 1];

            // scan free columns: update minv/way, track local argmin.
            double bestv = DINF;
            int    bestj = Q_ + 1;
#pragma unroll
            for (int k = 0; k < NK; ++k) {
                if (!((used >> k) & 1u)) {
                    const int q = (k << 6) + lane;
                    const float pr = sProb[q * NCLS + lab];
                    const float4 p4 = pbr[k];
                    float cb = fabsf(p4.x - t4.x);
                    cb = cb + fabsf(p4.y - t4.y);
                    cb = cb + fabsf(p4.z - t4.z);
                    cb = cb + fabsf(p4.w - t4.w);
                    const float cost = cb - pr;
                    const double cur = (double)cost - u_i0 - v[k];
                    if (cur < minv[k]) { minv[k] = cur; sWay[q + 1] = j0; }
                    const double mv = minv[k];
                    if (mv < bestv) { bestv = mv; bestj = q + 1; }
                }
            }
            // wave argmin, first-index tie-break; result lands in every lane
#pragma unroll
            for (int m = 1; m < 64; m <<= 1) {
                const double ov = __shfl_xor(bestv, m);
                const int    oj = __shfl_xor(bestj, m);
                if (ov < bestv || (ov == bestv && oj < bestj)) { bestv = ov; bestj = oj; }
            }
            const double delta = bestv;
            const int    j1    = bestj;

            // u[p[used]] += delta; v[used] -= delta; minv[free] -= delta
            const unsigned um = used & validMask;
#pragma unroll
            for (int k = 0; k < NK; ++k) {
                if ((used >> k) & 1u) v[k] -= delta; else minv[k] -= delta;
                if ((um >> k) & 1u) {
                    const int row = sP[(k << 6) + lane + 1];  // distinct rows -> no race
                    sU[row] += delta;
                }
            }
            if (lane == 0) sU[i] += delta;       // column 0: p[0] = i
            __syncthreads();
            const int pj1 = sP[j1];              // broadcast read
            if (pj1 == 0) { j0 = j1; break; }
            j0 = j1; i0 = pj1;
        }
        if (lane == 0) {                         // augmenting path (short, serial)
            int jj = j0;
            while (jj != 0) {
                const int j1 = sWay[jj];
                sP[jj] = (j1 == 0) ? i : sP[j1];
                jj = j1;
            }
        }
        __syncthreads();
    }

    // ---- extract matching: pred query for each target ----
#pragma unroll
    for (int k = 0; k < NK; ++k) {
        if ((validMask >> k) & 1u) {
            const int j  = (k << 6) + lane + 1;
            const int pi = sP[j];
            if (pi > 0) sPred[pi - 1] = j - 1;
            sTc[j - 1] = NCLS;
        }
    }
    __syncthreads();
    for (int t = lane; t < T_; t += 64) sTc[sPred[t]] = sLab[t];  // sPred distinct
    __syncthreads();

    // ---- weighted CE over all queries ----
    double swn = 0.0, sw = 0.0;
#pragma unroll
    for (int k = 0; k < NK; ++k) {
        if ((validMask >> k) & 1u) {
            const int   q   = (k << 6) + lane;
            const int   c   = sTc[q];
            const float xv  = pcb[q * NCLS1 + c];
            const float nll = sLse[q] - xv;          // -log_softmax[tc]
            const double w  = (c == NCLS) ? (double)0.05f : 1.0;
            swn += w * (double)nll;
            sw  += w;
        }
    }

    // ---- bbox L1 + GIoU over matched pairs ----
    double l1s = 0.0, gs = 0.0;
    for (int t = lane; t < T_; t += 64) {
        const int q = sPred[t];
        const float4 p4 = reinterpret_cast<const float4*>(pbb)[q];
        const float4 t4 = sTb4[t];
        l1s += (double)fabsf(p4.x - t4.x) + (double)fabsf(p4.y - t4.y)
             + (double)fabsf(p4.z - t4.z) + (double)fabsf(p4.w - t4.w);
        const float ax1 = p4.x - 0.5f * p4.z, ay1 = p4.y - 0.5f * p4.w;
        const float ax2 = p4.x + 0.5f * p4.z, ay2 = p4.y + 0.5f * p4.w;
        const float bx1 = t4.x - 0.5f * t4.z, by1 = t4.y - 0.5f * t4.w;
        const float bx2 = t4.x + 0.5f * t4.z, by2 = t4.y + 0.5f * t4.w;
        const double a1 = (double)(ax2 - ax1) * (double)(ay2 - ay1);
        const double a2 = (double)(bx2 - bx1) * (double)(by2 - by1);
        const double ltx = fmax((double)ax1, (double)bx1);
        const double lty = fmax((double)ay1, (double)by1);
        const double rbx = fmin((double)ax2, (double)bx2);
        const double rby = fmin((double)ay2, (double)by2);
        const double iw = fmax(rbx - ltx, 0.0), ih = fmax(rby - lty, 0.0);
        const double inter = iw * ih;
        const double uni   = a1 + a2 - inter;
        const double iou   = inter / uni;
        const double cx1 = fmin((double)ax1, (double)bx1);
        const double cy1 = fmin((double)ay1, (double)by1);
        const double cx2 = fmax((double)ax2, (double)bx2);
        const double cy2 = fmax((double)ay2, (double)by2);
        const double ac  = (cx2 - cx1) * (cy2 - cy1);
        const double giou = iou - (ac - uni) / ac;
        gs += 1.0 - giou;
    }

    const double swnT = waveSum(swn);
    const double swT  = waveSum(sw);
    const double l1T  = waveSum(l1s);
    const double gsT  = waveSum(gs);
    if (lane == 0) {
        const double cls = swnT / swT;
        const double bb  = 5.0 * (l1T / (double)(T_ * 4)) + 2.0 * (gsT / (double)T_);
        perImg[b] = cls + bb;
    }
}

extern "C" __global__ __launch_bounds__(64)
void detr_finalize(const double* __restrict__ perImg, float* __restrict__ out)
{
    const int l = threadIdx.x;   // 64 threads, one wave
    double v = perImg[l];
#pragma unroll
    for (int off = 32; off > 0; off >>= 1) v += __shfl_down(v, off);
    if (l == 0) out[0] = (float)(v / 8192.0);
}

extern "C" void kernel_launch(void* const* d_in, const int* in_sizes, int n_in,
                              void* d_out, int out_size, void* d_ws, size_t ws_size,
                              hipStream_t stream) {
    const float* pc  = (const float*)d_in[0];   // predicted_class [64,900,14]
    const float* pbx = (const float*)d_in[1];   // predicted_bbox  [64,900,4]
    const int*   tl  = (const int*)  d_in[2];   // target_labels   [64,128]
    const float* tbx = (const float*)d_in[3];   // target_boxes    [64,128,4]
    double* wsl = (double*)d_ws;                // 64 doubles of scratch
    (void)in_sizes; (void)n_in; (void)out_size; (void)ws_size;

    detr_hungarian_loss<<<dim3(B_), dim3(64), 0, stream>>>(pc, pbx, tl, tbx, wsl);
    detr_finalize<<<dim3(1), dim3(64), 0, stream>>>(wsl, (float*)d_out);
}

// Round 3
// 206.602 us; speedup vs baseline: 2.3489x; 2.3467x over previous
//
#include <hip/hip_runtime.h>
#include <math.h>

// Problem constants (from reference): B=64, Q=900, T=128, NUM_CLASSES=13
#define B_    64
#define Q_    900
#define T_    128
#define NCLS  13
#define NCLS1 14
#define NTH   256
#define NWV   (NTH / 64)

// Block-wide f64 sum; result valid on tid 0. All threads must call.
__device__ __forceinline__ double blockSum(double v, double* sAcc, int tid) {
#pragma unroll
    for (int off = 32; off > 0; off >>= 1) v += __shfl_down(v, off);
    if ((tid & 63) == 0) sAcc[tid >> 6] = v;
    __syncthreads();
    if (tid == 0) {
#pragma unroll
        for (int w = 1; w < NWV; ++w) v += sAcc[w];
    }
    __syncthreads();
    return v;
}

// One block per image. JV Hungarian with row-reduction + greedy init:
// u[r] = min_j cost[r][j] (parallel), greedy zero-reduced-cost assignment,
// then successive-shortest-path Dijkstra ONLY for collided rows. Since the
// optimum is unique for continuous random costs, this returns the identical
// assignment to the reference's plain e-maxx JV. Cost entries f32 in the
// reference's op order; duals f64; np.argmin first-index tie-break.
extern "C" __global__ __launch_bounds__(NTH)
void detr_hungarian_loss(const float* __restrict__ pc,    // [B,Q,14]
                         const float* __restrict__ pbx,   // [B,Q,4]
                         const int*   __restrict__ tl,    // [B,T]
                         const float* __restrict__ tbx,   // [B,T,4]
                         double* __restrict__ perImg)     // [B]
{
    const int b   = blockIdx.x;
    const int tid = threadIdx.x;

    __shared__ float  sProb[Q_ * NCLS];   // softmax probs, classes 0..12
    __shared__ float  sLse[Q_];           // logsumexp per query (for CE)
    __shared__ float4 sPb4[Q_];           // predicted boxes
    __shared__ float4 sTb4[T_];           // target boxes
    __shared__ int    sLab[T_];           // target labels
    __shared__ double sV[Q_ + 1];         // column duals
    __shared__ double sMinv[Q_ + 1];
    __shared__ double sU[T_ + 1];         // row duals (1-based)
    __shared__ int    sP[Q_ + 1];         // col -> assigned row (1-based)
    __shared__ int    sWay[Q_ + 1];       // reused as tc[] later
    __shared__ unsigned char sUsed[Q_ + 1];
    __shared__ int    sAmin[T_];          // row -> argmin column (0-based)
    __shared__ int    sFreeRows[T_];      // rows needing Dijkstra
    __shared__ int    sNumFree;
    __shared__ int    sPred[T_];          // target t -> matched query
    __shared__ double sRv[NWV];
    __shared__ int    sRi[NWV];
    __shared__ double sAcc[NWV];

    const double DINF = __builtin_inf();

    const float* pcb = pc  + (size_t)b * Q_ * NCLS1;
    const float* pbb = pbx + (size_t)b * Q_ * 4;
    const float* tbb = tbx + (size_t)b * T_ * 4;
    const int*   tlb = tl  + (size_t)b * T_;

    // ---- stage inputs + f32 softmax (same op order as jax.nn.softmax) ----
    for (int q = tid; q < Q_; q += NTH) {
        float x[NCLS1];
#pragma unroll
        for (int c = 0; c < NCLS1; ++c) x[c] = pcb[q * NCLS1 + c];
        float mx = x[0];
#pragma unroll
        for (int c = 1; c < NCLS1; ++c) mx = fmaxf(mx, x[c]);
        float ex[NCLS1];
        float sum = 0.f;
#pragma unroll
        for (int c = 0; c < NCLS1; ++c) { ex[c] = expf(x[c] - mx); sum += ex[c]; }
#pragma unroll
        for (int c = 0; c < NCLS; ++c) sProb[q * NCLS + c] = ex[c] / sum;
        sLse[q] = mx + logf(sum);
        sPb4[q] = reinterpret_cast<const float4*>(pbb)[q];
    }
    for (int t = tid; t < T_; t += NTH) {
        sLab[t] = tlb[t];
        sTb4[t] = reinterpret_cast<const float4*>(tbb)[t];
    }
    for (int j = tid; j <= Q_; j += NTH) { sV[j] = 0.0; sP[j] = 0; }
    __syncthreads();

    // ---- phase 1: row minima (u[r] = min_j cost[r][j]) + argmin column ----
    {
        const int r    = tid >> 1;        // 0..127, two threads per row
        const int half = tid & 1;
        const float4 t4  = sTb4[r];
        const int    lab = sLab[r];
        float bv = __builtin_inff();
        int   bj = Q_;
        const int q0 = half * (Q_ / 2);
        for (int q = q0; q < q0 + (Q_ / 2); ++q) {
            const float4 p4 = sPb4[q];
            float cb = fabsf(p4.x - t4.x);
            cb = cb + fabsf(p4.y - t4.y);
            cb = cb + fabsf(p4.z - t4.z);
            cb = cb + fabsf(p4.w - t4.w);
            const float cost = cb - sProb[q * NCLS + lab];
            if (cost < bv) { bv = cost; bj = q; }
        }
        const float ov = __shfl_xor(bv, 1);
        const int   oj = __shfl_xor(bj, 1);
        if (ov < bv || (ov == bv && oj < bj)) { bv = ov; bj = oj; }
        if (half == 0) { sU[r + 1] = (double)bv; sAmin[r] = bj; }
    }
    __syncthreads();

    // ---- greedy zero-reduced-cost assignment; collect collided rows ----
    if (tid == 0) {
        int nf = 0;
        for (int r = 0; r < T_; ++r) {
            const int j = sAmin[r] + 1;
            if (sP[j] == 0) sP[j] = r + 1;
            else            sFreeRows[nf++] = r;
        }
        sNumFree = nf;
    }
    __syncthreads();
    const int numFree = sNumFree;

    // ---- Dijkstra augmentation for each unassigned row ----
    for (int fi = 0; fi < numFree; ++fi) {
        const int i = sFreeRows[fi] + 1;       // 1-based row
        if (tid == 0) sP[0] = i;
        for (int j = tid; j <= Q_; j += NTH) {
            sMinv[j] = DINF;
            sUsed[j] = (j == 0) ? 1 : 0;
        }
        __syncthreads();
        int j0 = 0, i0 = i;
        for (;;) {
            const double u_i0 = sU[i0];
            const float4 t4   = sTb4[i0 - 1];
            const int    lab  = sLab[i0 - 1];

            // scan free columns: update minv/way, track local argmin.
            double bestv = DINF;
            int    bestj = Q_ + 1;
            for (int j = 1 + tid; j <= Q_; j += NTH) {
                if (!sUsed[j]) {
                    const int q = j - 1;
                    const float4 p4 = sPb4[q];
                    float cb = fabsf(p4.x - t4.x);
                    cb = cb + fabsf(p4.y - t4.y);
                    cb = cb + fabsf(p4.z - t4.z);
                    cb = cb + fabsf(p4.w - t4.w);
                    const float cost = cb - sProb[q * NCLS + lab];
                    const double cur = (double)cost - u_i0 - sV[j];
                    double mv = sMinv[j];
                    if (cur < mv) { sMinv[j] = cur; sWay[j] = j0; mv = cur; }
                    if (mv < bestv) { bestv = mv; bestj = j; }
                }
            }
            // per-wave argmin (first-index tie-break), then all-thread merge
#pragma unroll
            for (int m = 1; m < 64; m <<= 1) {
                const double ov = __shfl_xor(bestv, m);
                const int    oj = __shfl_xor(bestj, m);
                if (ov < bestv || (ov == bestv && oj < bestj)) { bestv = ov; bestj = oj; }
            }
            if ((tid & 63) == 0) { sRv[tid >> 6] = bestv; sRi[tid >> 6] = bestj; }
            __syncthreads();                        // barrier A
            double dv = sRv[0]; int dj = sRi[0];
#pragma unroll
            for (int w = 1; w < NWV; ++w) {
                if (sRv[w] < dv || (sRv[w] == dv && sRi[w] < dj)) { dv = sRv[w]; dj = sRi[w]; }
            }
            const double delta = dv;
            const int    i0n   = sP[dj];            // sP not written below
            // u[p[used]] += delta; v[used] -= delta; minv[free] -= delta.
            // dj stays "free" for THIS update (reference marks used next iter);
            // its owner flips used[dj] after applying the minv decrement.
            for (int j = tid; j <= Q_; j += NTH) {
                if (sUsed[j]) { sU[sP[j]] += delta; sV[j] -= delta; }
                else          { sMinv[j] -= delta; if (j == dj) sUsed[j] = 1; }
            }
            __syncthreads();                        // barrier B
            if (i0n == 0) { j0 = dj; break; }
            j0 = dj; i0 = i0n;
        }
        if (tid == 0) {                             // augmenting path (short)
            int jj = j0;
            while (jj != 0) {
                const int j1 = sWay[jj];
                sP[jj] = sP[j1];                    // sP[0] == i
                jj = j1;
            }
        }
        __syncthreads();
    }

    // ---- extract matching: pred query for each target ----
    for (int j = 1 + tid; j <= Q_; j += NTH) {
        const int pi = sP[j];
        if (pi > 0) sPred[pi - 1] = j - 1;
    }
    __syncthreads();

    // ---- tc[] (reuse sWay): NUM_CLASSES default, matched queries get label ----
    int* sTc = sWay;
    for (int q = tid; q < Q_; q += NTH) sTc[q] = NCLS;
    __syncthreads();
    for (int t = tid; t < T_; t += NTH) sTc[sPred[t]] = sLab[t];  // sPred distinct
    __syncthreads();

    // ---- weighted CE over all queries ----
    double swn = 0.0, sw = 0.0;
    for (int q = tid; q < Q_; q += NTH) {
        const int   c   = sTc[q];
        const float xv  = pcb[q * NCLS1 + c];
        const float nll = sLse[q] - xv;              // -log_softmax[tc]
        const double w  = (c == NCLS) ? (double)0.05f : 1.0;
        swn += w * (double)nll;
        sw  += w;
    }

    // ---- bbox L1 + GIoU over matched pairs ----
    double l1s = 0.0, gs = 0.0;
    for (int t = tid; t < T_; t += NTH) {
        const int q = sPred[t];
        const float4 p4 = sPb4[q];
        const float4 t4 = sTb4[t];
        l1s += (double)fabsf(p4.x - t4.x) + (double)fabsf(p4.y - t4.y)
             + (double)fabsf(p4.z - t4.z) + (double)fabsf(p4.w - t4.w);
        const float ax1 = p4.x - 0.5f * p4.z, ay1 = p4.y - 0.5f * p4.w;
        const float ax2 = p4.x + 0.5f * p4.z, ay2 = p4.y + 0.5f * p4.w;
        const float bx1 = t4.x - 0.5f * t4.z, by1 = t4.y - 0.5f * t4.w;
        const float bx2 = t4.x + 0.5f * t4.z, by2 = t4.y + 0.5f * t4.w;
        const double a1 = (double)(ax2 - ax1) * (double)(ay2 - ay1);
        const double a2 = (double)(bx2 - bx1) * (double)(by2 - by1);
        const double ltx = fmax((double)ax1, (double)bx1);
        const double lty = fmax((double)ay1, (double)by1);
        const double rbx = fmin((double)ax2, (double)bx2);
        const double rby = fmin((double)ay2, (double)by2);
        const double iw = fmax(rbx - ltx, 0.0), ih = fmax(rby - lty, 0.0);
        const double inter = iw * ih;
        const double uni   = a1 + a2 - inter;
        const double iou   = inter / uni;
        const double cx1 = fmin((double)ax1, (double)bx1);
        const double cy1 = fmin((double)ay1, (double)by1);
        const double cx2 = fmax((double)ax2, (double)bx2);
        const double cy2 = fmax((double)ay2, (double)by2);
        const double ac  = (cx2 - cx1) * (cy2 - cy1);
        const double giou = iou - (ac - uni) / ac;
        gs += 1.0 - giou;
    }

    const double swnT = blockSum(swn, sAcc, tid);
    const double swT  = blockSum(sw,  sAcc, tid);
    const double l1T  = blockSum(l1s, sAcc, tid);
    const double gsT  = blockSum(gs,  sAcc, tid);
    if (tid == 0) {
        const double cls = swnT / swT;
        const double bb  = 5.0 * (l1T / (double)(T_ * 4)) + 2.0 * (gsT / (double)T_);
        perImg[b] = cls + bb;
    }
}

extern "C" __global__ __launch_bounds__(64)
void detr_finalize(const double* __restrict__ perImg, float* __restrict__ out)
{
    const int l = threadIdx.x;   // 64 threads, one wave
    double v = perImg[l];
#pragma unroll
    for (int off = 32; off > 0; off >>= 1) v += __shfl_down(v, off);
    if (l == 0) out[0] = (float)(v / 8192.0);
}

extern "C" void kernel_launch(void* const* d_in, const int* in_sizes, int n_in,
                              void* d_out, int out_size, void* d_ws, size_t ws_size,
                              hipStream_t stream) {
    const float* pc  = (const float*)d_in[0];   // predicted_class [64,900,14]
    const float* pbx = (const float*)d_in[1];   // predicted_bbox  [64,900,4]
    const int*   tl  = (const int*)  d_in[2];   // target_labels   [64,128]
    const float* tbx = (const float*)d_in[3];   // target_boxes    [64,128,4]
    double* wsl = (double*)d_ws;                // 64 doubles of scratch
    (void)in_sizes; (void)n_in; (void)out_size; (void)ws_size;

    detr_hungarian_loss<<<dim3(B_), dim3(NTH), 0, stream>>>(pc, pbx, tl, tbx, wsl);
    detr_finalize<<<dim3(1), dim3(64), 0, stream>>>(wsl, (float*)d_out);
}